// Round 2
// baseline (148.505 us; speedup 1.0000x reference)
//
#include <hip/hip_runtime.h>
#include <hip/hip_bf16.h>

// MSEL_Feat: fused per-identity loss.
//   N=8192, D=2048, num_pos=4, id_num=2048.
//   All distances derive from per-identity sums:
//     S = sum_p r_p, T = sum_p ir_p
//     loo_p       = (S - r_p)/3          (and loo_ir == loo_rgb, per reference bug)
//     center_rgb  = S/4, center_ir = T/4
//   Needed reductions per identity (25 scalars):
//     rr[p]=|r_p|^2, ii[p]=|ir_p|^2, sr[p]=S.r_p, si[p]=S.ir_p,
//     ri[p]=r_p.ir_p, rt[p]=r_p.T, tt=|T|^2   (|S|^2 = sum_p sr[p])

constexpr int D    = 2048;
constexpr int NPOS = 4;
constexpr int TPB  = 256;
constexpr int VEC4 = D / 4;          // 512 float4 per row
constexpr int ITER = VEC4 / TPB;     // 2 float4 chunks per thread per row
constexpr int NACC = 25;

__global__ void zero_out_kernel(float* out) { out[0] = 0.0f; }

__global__ void __launch_bounds__(TPB) msel_feat_kernel(
        const float* __restrict__ in1,   // RGB feats [N, D]
        const float* __restrict__ in2,   // IR  feats [N, D]
        float* __restrict__ out) {
    const long id = blockIdx.x;
    const float* __restrict__ ra = in1 + id * (long)(NPOS * D);
    const float* __restrict__ rb = in2 + id * (long)(NPOS * D);

    float acc[NACC];
#pragma unroll
    for (int k = 0; k < NACC; ++k) acc[k] = 0.0f;

#pragma unroll
    for (int it = 0; it < ITER; ++it) {
        const int c = (threadIdx.x + it * TPB) * 4;   // float offset in row
        float rv[NPOS][4], iv[NPOS][4];
#pragma unroll
        for (int p = 0; p < NPOS; ++p) {
            *reinterpret_cast<float4*>(&rv[p][0]) =
                *reinterpret_cast<const float4*>(ra + p * D + c);
            *reinterpret_cast<float4*>(&iv[p][0]) =
                *reinterpret_cast<const float4*>(rb + p * D + c);
        }
#pragma unroll
        for (int e = 0; e < 4; ++e) {
            const float s = rv[0][e] + rv[1][e] + rv[2][e] + rv[3][e];
            const float t = iv[0][e] + iv[1][e] + iv[2][e] + iv[3][e];
            acc[24] = fmaf(t, t, acc[24]);                 // |T|^2
#pragma unroll
            for (int p = 0; p < NPOS; ++p) {
                const float x = rv[p][e];
                const float y = iv[p][e];
                acc[0  + p] = fmaf(x, x, acc[0  + p]);     // rr
                acc[4  + p] = fmaf(y, y, acc[4  + p]);     // ii
                acc[8  + p] = fmaf(s, x, acc[8  + p]);     // sr
                acc[12 + p] = fmaf(s, y, acc[12 + p]);     // si
                acc[16 + p] = fmaf(x, y, acc[16 + p]);     // ri
                acc[20 + p] = fmaf(x, t, acc[20 + p]);     // rt
            }
        }
    }

    // 64-lane wave reduce each accumulator
#pragma unroll
    for (int k = 0; k < NACC; ++k) {
        float v = acc[k];
#pragma unroll
        for (int off = 32; off > 0; off >>= 1) v += __shfl_down(v, off, 64);
        acc[k] = v;
    }

    __shared__ float lds[TPB / 64][NACC];
    const int wave = threadIdx.x >> 6;
    const int lane = threadIdx.x & 63;
    if (lane == 0) {
#pragma unroll
        for (int k = 0; k < NACC; ++k) lds[wave][k] = acc[k];
    }
    __syncthreads();

    if (threadIdx.x == 0) {
        float tot[NACC];
#pragma unroll
        for (int k = 0; k < NACC; ++k)
            tot[k] = lds[0][k] + lds[1][k] + lds[2][k] + lds[3][k];

        const float ss = tot[8] + tot[9] + tot[10] + tot[11];  // |S|^2
        const float tt = tot[24];                              // |T|^2
        float contrib = 0.0f;
#pragma unroll
        for (int p = 0; p < NPOS; ++p) {
            const float rr = tot[0 + p];
            const float ii = tot[4 + p];
            const float sr = tot[8 + p];
            const float si = tot[12 + p];
            const float ri = tot[16 + p];
            const float rt = tot[20 + p];

            // |loo_p|^2 = (|S|^2 - 2 S.r_p + |r_p|^2)/9
            const float b2loo = (ss - 2.0f * sr + rr) * (1.0f / 9.0f);
            // r_p.loo_p = (S.r_p - |r_p|^2)/3 ; ir_p.loo_p = (S.ir_p - r_p.ir_p)/3
            const float sq_intra_rgb = rr + b2loo - 2.0f * ((sr - rr) * (1.0f / 3.0f));
            const float sq_intra_ir  = ii + b2loo - 2.0f * ((si - ri) * (1.0f / 3.0f));
            // cross: centers are T/4 (for r) and S/4 (for ir)
            const float sq_cross_rgb = rr + tt * 0.0625f - 0.5f * rt;
            const float sq_cross_ir  = ii + ss * 0.0625f - 0.5f * si;

            const float d_ir_rgb = sqrtf(fmaxf(sq_intra_rgb, 1e-12f));
            const float d_ir_ir  = sqrtf(fmaxf(sq_intra_ir,  1e-12f));
            const float d_cr_rgb = sqrtf(fmaxf(sq_cross_rgb, 1e-12f));
            const float d_cr_ir  = sqrtf(fmaxf(sq_cross_ir,  1e-12f));

            const float e1 = d_cr_rgb - d_ir_rgb;
            const float e2 = d_cr_ir  - d_ir_ir;
            contrib += e1 * e1 + e2 * e2;
        }
        // loss = sum / N / 2, N = 8192
        atomicAdd(out, contrib * (1.0f / 16384.0f));
    }
}

extern "C" void kernel_launch(void* const* d_in, const int* in_sizes, int n_in,
                              void* d_out, int out_size, void* d_ws, size_t ws_size,
                              hipStream_t stream) {
    const float* in1 = (const float*)d_in[0];
    const float* in2 = (const float*)d_in[1];
    float* out = (float*)d_out;

    const int id_num = in_sizes[0] / (NPOS * D);   // 2048

    zero_out_kernel<<<1, 1, 0, stream>>>(out);
    msel_feat_kernel<<<id_num, TPB, 0, stream>>>(in1, in2, out);
}